// Round 3
// baseline (944.706 us; speedup 1.0000x reference)
//
#include <hip/hip_runtime.h>

// Problem constants (from reference setup_inputs): B=8, H=512, W=512, C=16, fp32.
#define BB 8
#define HH 512
#define WW 512
#define CC 16

// Gather tiling: each block owns a TH x TW output tile, scans the
// (TH+2R) x (TW+2R) source neighborhood, accumulates in LDS.
#define TH 16
#define TW 32
#define RR 16
#define SH (TH + 2*RR)        // 48 scan rows
#define SW (TW + 2*RR)        // 64 scan cols
#define NSCAN (SH * SW)       // 3072 candidates per block
#define CPAD 17               // channel pad: 17 coprime w/ 32 banks -> conflict-free-ish

// Source classification. MUST be the identical expression in both kernels so
// they partition sources exactly. |u|<=15 => both corners within +-16 of the
// source pixel => covered by the halo scan.
__device__ __forceinline__ bool flow_small(float ux, float uy) {
    return (fabsf(ux) <= 15.0f) & (fabsf(uy) <= 15.0f);
}

// Pass 1: tiled gather. Writes every output element with a plain store
// (no zero-fill needed; d_out poison is fully overwritten).
__global__ __launch_bounds__(256) void warp_t_gather(
    const float* __restrict__ gout,
    const float* __restrict__ u,
    float* __restrict__ gx)
{
    __shared__ float acc[TH * TW * CPAD];     // 512*17*4 = 34816 B
    __shared__ unsigned short lst[NSCAN];     // 6144 B (worst-case capacity)
    __shared__ int cnt;

    const int tid = threadIdx.x;
    const int bid = blockIdx.x;               // 4096 blocks = 8 imgs * 32 * 16 tiles
    const int b   = bid >> 9;                 // 512 tiles per image
    const int t   = bid & 511;
    const int ty0 = (t >> 4) * TH;            // 32 vertical tiles
    const int tx0 = (t & 15) * TW;            // 16 horizontal tiles

    for (int i = tid; i < TH * TW * CPAD; i += 256) acc[i] = 0.0f;
    if (tid == 0) cnt = 0;
    __syncthreads();

    const float2* ub = (const float2*)(u) + (size_t)b * (HH * WW);

    // Phase A: scan halo region, compact hit-sources into lst.
    for (int i = tid; i < NSCAN; i += 256) {
        const int sy = ty0 - RR + (i >> 6);   // i / SW, SW==64
        const int sx = tx0 - RR + (i & 63);
        if ((unsigned)sy >= (unsigned)HH || (unsigned)sx >= (unsigned)WW) continue;
        const float2 uv = ub[sy * WW + sx];
        if (!flow_small(uv.x, uv.y)) continue;
        const float fx = (float)sx + uv.x;
        const float fy = (float)sy + uv.y;
        const int lx0 = (int)floorf(fx) - tx0;
        const int ly0 = (int)floorf(fy) - ty0;
        // 2x2 corner footprint overlaps [0,TW) x [0,TH)?
        if (lx0 >= -1 && lx0 < TW && ly0 >= -1 && ly0 < TH) {
            const int k = atomicAdd(&cnt, 1);
            lst[k] = (unsigned short)i;
        }
    }
    __syncthreads();
    const int n = cnt;

    // Phase B: one thread per hit source -> 4 corners x 16 ch LDS atomics.
    for (int e = tid; e < n; e += 256) {
        const int i  = lst[e];
        const int sy = ty0 - RR + (i >> 6);
        const int sx = tx0 - RR + (i & 63);
        const float2 uv = ub[sy * WW + sx];
        const float fx = (float)sx + uv.x;
        const float fy = (float)sy + uv.y;
        const float x0f = floorf(fx);
        const float y0f = floorf(fy);
        const float wx = fx - x0f;
        const float wy = fy - y0f;
        const int lx0 = (int)x0f - tx0;
        const int ly0 = (int)y0f - ty0;

        const float4* gp =
            (const float4*)(gout + ((size_t)((b * HH + sy) * WW + sx) << 4));
        const float4 g0 = gp[0], g1 = gp[1], g2 = gp[2], g3 = gp[3];
        float gg[16] = { g0.x, g0.y, g0.z, g0.w,
                         g1.x, g1.y, g1.z, g1.w,
                         g2.x, g2.y, g2.z, g2.w,
                         g3.x, g3.y, g3.z, g3.w };
        const float w00 = (1.0f - wy) * (1.0f - wx);
        const float w01 = (1.0f - wy) * wx;
        const float w10 = wy * (1.0f - wx);
        const float w11 = wy * wx;
        const float ws4[4] = { w00, w01, w10, w11 };

#pragma unroll
        for (int cor = 0; cor < 4; cor++) {
            const int lx = lx0 + (cor & 1);
            const int ly = ly0 + (cor >> 1);
            if ((unsigned)lx < (unsigned)TW && (unsigned)ly < (unsigned)TH) {
                const float w = ws4[cor];
                const int base = (ly * TW + lx) * CPAD;
#pragma unroll
                for (int j = 0; j < 16; j++)
                    atomicAdd(&acc[base + j], w * gg[j]);
            }
        }
    }
    __syncthreads();

    // Epilogue: tile -> global, plain coalesced stores (overwrites poison).
    for (int i = tid; i < TH * TW * CC; i += 256) {
        const int pix = i >> 4;
        const int c   = i & 15;
        const int ly  = pix >> 5;              // TW==32
        const int lx  = pix & 31;
        gx[((size_t)((b * HH + ty0 + ly) * WW + tx0 + lx) << 4) + c] =
            acc[pix * CPAD + c];
    }
}

// Pass 2: exact fallback for the rare |u|>15 sources (global atomics; ~1e-4
// of pixels). Runs after the gather's plain stores (stream-ordered).
__global__ __launch_bounds__(256) void warp_t_outlier(
    const float* __restrict__ gout,
    const float* __restrict__ u,
    float* __restrict__ gx)
{
    const int p = blockIdx.x * 256 + threadIdx.x;   // pixel index, exact grid
    const float2 uv = ((const float2*)u)[p];
    if (flow_small(uv.x, uv.y)) return;

    const int x = p & (WW - 1);
    const int y = (p >> 9) & (HH - 1);
    const int b = p >> 18;
    const float fx = (float)x + uv.x;
    const float fy = (float)y + uv.y;
    const float x0f = floorf(fx);
    const float y0f = floorf(fy);
    const float wx = fx - x0f;
    const float wy = fy - y0f;
    const int x0 = (int)x0f;
    const int y0 = (int)y0f;

    const float* gp = gout + ((size_t)p << 4);
    const float ws4[4] = { (1.0f - wy) * (1.0f - wx), (1.0f - wy) * wx,
                           wy * (1.0f - wx),          wy * wx };
#pragma unroll
    for (int cor = 0; cor < 4; cor++) {
        const int xx = x0 + (cor & 1);
        const int yy = y0 + (cor >> 1);
        if ((unsigned)xx < (unsigned)WW && (unsigned)yy < (unsigned)HH) {
            const float w = ws4[cor];
            float* dst = gx + ((size_t)((b * HH + yy) * WW + xx) << 4);
#pragma unroll
            for (int j = 0; j < 16; j++)
                atomicAdd(dst + j, w * gp[j]);
        }
    }
}

extern "C" void kernel_launch(void* const* d_in, const int* in_sizes, int n_in,
                              void* d_out, int out_size, void* d_ws, size_t ws_size,
                              hipStream_t stream) {
    const float* gout = (const float*)d_in[0];   // grad_out [B,H,W,C]
    const float* u    = (const float*)d_in[1];   // flow     [B,H,W,2]
    float* gx = (float*)d_out;

    const int tiles = BB * (HH / TH) * (WW / TW);   // 4096
    warp_t_gather<<<tiles, 256, 0, stream>>>(gout, u, gx);

    const int pixels = BB * HH * WW;                // 2,097,152
    warp_t_outlier<<<pixels / 256, 256, 0, stream>>>(gout, u, gx);
}